// Round 1
// baseline (175.345 us; speedup 1.0000x reference)
//
#include <hip/hip_runtime.h>
#include <math.h>

#define B_    1024
#define L_    200
#define DIM_  100
#define NP    128          // padded N (100 -> 128)
#define K_    1024
#define NCH   16           // split-K chunks per GEMM
#define KCH   (K_ / NCH)   // 64 K-rows per chunk
#define BM    32
#define NTILE (B_ / BM)    // 32 M-tiles

// ---------------- Kernel 1: gather + mean-pool (float4 gathers) -------------
// relP[b,d] = (sum_l emb0[items[b,l]][d]) / slen[b]; emb idx 0 = zero row.
// Also zero-inits the atomic accumulators tM/preM and the tile counters
// (must happen every iteration: harness poisons the workspace between runs;
// stream order guarantees completion before the GEMMs' atomics).
__global__ __launch_bounds__(256) void gather_pool_k(
    const float* __restrict__ emb, const int* __restrict__ items,
    const float* __restrict__ slen, float4* __restrict__ relP4,
    float4* __restrict__ tM4, float4* __restrict__ preM4,
    int* __restrict__ cnt) {
  const int b = blockIdx.x;
  const int t = threadIdx.x;
  const int s = t >> 5;            // item stream 0..7
  const int c = t & 31;            // float4 col, valid c<25
  if (t < 32) {                    // zero accumulators for this row
    const float4 z = make_float4(0.f, 0.f, 0.f, 0.f);
    tM4[b * 32 + t] = z;
    preM4[b * 32 + t] = z;
    if (b == 0) cnt[t] = 0;        // 32 tile counters
  }
  const int* __restrict__ row = items + b * L_;
  float4 acc = make_float4(0.f, 0.f, 0.f, 0.f);
  if (c < 25) {
    #pragma unroll
    for (int j = 0; j < L_ / 8; ++j) {         // 25 items per thread
      const int idx = row[s + 8 * j];
      if (idx > 0) {
        const float4 v = *(const float4*)&emb[(size_t)(idx - 1) * DIM_ + c * 4];
        acc.x += v.x; acc.y += v.y; acc.z += v.z; acc.w += v.w;
      }
    }
  }
  __shared__ float4 sm[8][32];                 // 4 KB
  sm[s][c] = acc;
  __syncthreads();
  if (s < 4) {
    float4 o = sm[s + 4][c];
    sm[s][c].x += o.x; sm[s][c].y += o.y; sm[s][c].z += o.z; sm[s][c].w += o.w;
  }
  __syncthreads();
  if (s < 2) {
    float4 o = sm[s + 2][c];
    sm[s][c].x += o.x; sm[s][c].y += o.y; sm[s][c].z += o.z; sm[s][c].w += o.w;
  }
  __syncthreads();
  if (s == 0) {
    float4 a0 = sm[0][c], a1 = sm[1][c];
    const float inv = 1.f / slen[b];
    float4 r;
    r.x = (a0.x + a1.x) * inv; r.y = (a0.y + a1.y) * inv;
    r.z = (a0.z + a1.z) * inv; r.w = (a0.w + a1.w) * inv;
    relP4[b * 32 + c] = (c < 25) ? r : make_float4(0.f, 0.f, 0.f, 0.f);
  }
}

// ------------- Kernel 2/3: split-K GEMM, atomic-accumulate into C ----------
// A: [1024][1024] row-major, Bm: [1024][NP], C: [1024][NP] (pre-zeroed).
// FINAL=1: last block per M-tile (counter) applies SELU + row L2-norm and
// writes out[1024][100]. Counter pattern: release fence -> atomicAdd(cnt)
// -> acquire fence -> plain re-read of the reduced 32x128 tile.
template <int FINAL>
__global__ __launch_bounds__(256) void gemm_splitk_k(
    const float* __restrict__ A,
    const float* __restrict__ Bm,
    float* __restrict__ C,
    int* __restrict__ cnt,
    float* __restrict__ out) {
  __shared__ float As[BM][KCH];   // 8 KB
  __shared__ float Bs[KCH][NP];   // 32 KB
  const int t  = threadIdx.x;
  const int m0 = blockIdx.x * BM;
  const int k0 = blockIdx.y * KCH;
  const int tc = t & 31;          // col group: cols tc*4 .. tc*4+3
  const int tr = t >> 5;          // 0..7 : rows tr*4 .. tr*4+3

  // stage A chunk: 2048 floats = 512 float4, 2 per thread
  #pragma unroll
  for (int q = 0; q < 2; ++q) {
    const int f = t + q * 256;            // 0..511
    const int r = f >> 4, kk = (f & 15) * 4;
    *(float4*)&As[r][kk] = *(const float4*)&A[(size_t)(m0 + r) * K_ + (k0 + kk)];
  }
  // stage B chunk: 8192 floats = 2048 float4, 8 per thread, coalesced
  #pragma unroll
  for (int q = 0; q < 8; ++q) {
    const int f = t + q * 256;            // 0..2047
    const int r = f >> 5, cc = (f & 31) * 4;
    *(float4*)&Bs[r][cc] = *(const float4*)&Bm[(size_t)(k0 + r) * NP + cc];
  }
  __syncthreads();

  float acc[4][4] = {};
  #pragma unroll
  for (int kk4 = 0; kk4 < KCH; kk4 += 4) {
    float a[4][4], bb[4][4];
    #pragma unroll
    for (int i = 0; i < 4; ++i)      // A frag: 32-lane broadcast (free)
      *(float4*)a[i] = *(const float4*)&As[tr * 4 + i][kk4];
    #pragma unroll
    for (int j = 0; j < 4; ++j)      // B frag: consecutive-lane b128
      *(float4*)bb[j] = *(const float4*)&Bs[kk4 + j][tc * 4];
    #pragma unroll
    for (int j = 0; j < 4; ++j)
      #pragma unroll
      for (int i = 0; i < 4; ++i)
        #pragma unroll
        for (int q = 0; q < 4; ++q)
          acc[i][q] += a[i][j] * bb[j][q];
  }

  // accumulate chunk product directly (device-scope fp32 atomics, coherent
  // across XCDs) -- no partial matrices, no reduce kernel.
  #pragma unroll
  for (int i = 0; i < 4; ++i)
    #pragma unroll
    for (int q = 0; q < 4; ++q)
      atomicAdd(&C[(size_t)(m0 + tr * 4 + i) * NP + tc * 4 + q], acc[i][q]);

  if (!FINAL) return;

  __threadfence();                       // release: my atomics visible
  __shared__ int lastFlag;
  if (t == 0) lastFlag = (atomicAdd(&cnt[blockIdx.x], 1) == NCH - 1);
  __syncthreads();
  if (!lastFlag) return;
  __threadfence();                       // acquire: see all blocks' atomics

  const float scale = 1.0507009873554804934f;
  const float alpha = 1.6732632423543772848f;
  #pragma unroll
  for (int rr = 0; rr < 4; ++rr) {
    const int row = m0 + tr * 4 + rr;    // 8 groups x 4 rows = 32 rows
    const float4 x = *(const float4*)&C[(size_t)row * NP + tc * 4];
    float4 sv;
    sv.x = (x.x > 0.f) ? scale * x.x : scale * alpha * expm1f(x.x);
    sv.y = (x.y > 0.f) ? scale * x.y : scale * alpha * expm1f(x.y);
    sv.z = (x.z > 0.f) ? scale * x.z : scale * alpha * expm1f(x.z);
    sv.w = (x.w > 0.f) ? scale * x.w : scale * alpha * expm1f(x.w);
    float ss = (tc < 25) ? (sv.x*sv.x + sv.y*sv.y + sv.z*sv.z + sv.w*sv.w) : 0.f;
    #pragma unroll
    for (int off = 16; off > 0; off >>= 1)   // 32-lane group (stays in half)
      ss += __shfl_xor(ss, off, 64);
    const float inv = 1.f / sqrtf(ss);
    if (tc < 25) {                       // rows are 400 B -> float4 aligned
      float4 o;
      o.x = sv.x * inv; o.y = sv.y * inv; o.z = sv.z * inv; o.w = sv.w * inv;
      *(float4*)&out[(size_t)row * DIM_ + tc * 4] = o;
    }
  }
}

extern "C" void kernel_launch(void* const* d_in, const int* in_sizes, int n_in,
                              void* d_out, int out_size, void* d_ws, size_t ws_size,
                              hipStream_t stream) {
  const float* emb   = (const float*)d_in[0];  // [50000][100]
  const int*   items = (const int*)d_in[1];    // [1024][200]
  const float* A     = (const float*)d_in[2];  // [1024][1024]
  const float* D     = (const float*)d_in[3];  // [1024][1024]
  const float* slen  = (const float*)d_in[4];  // [1024]
  float* out = (float*)d_out;                  // [1024][100]

  char* ws = (char*)d_ws;
  const size_t matB = (size_t)B_ * NP * sizeof(float);    // 512 KB
  float* relP = (float*)(ws);                             // [1024][128]
  float* tM   = (float*)(ws + 1 * matB);                  // [1024][128]
  float* preM = (float*)(ws + 2 * matB);                  // [1024][128]
  int*   cnt  = (int*)(ws + 3 * matB);                    // [32]

  // 1. rel = mean-pool(gather); zero tM/preM/cnt
  gather_pool_k<<<B_, 256, 0, stream>>>(emb, items, slen, (float4*)relP,
                                        (float4*)tM, (float4*)preM, cnt);
  // 2. tM += A_chunk @ rel  (atomic split-K; reassociated D@(A@rel))
  gemm_splitk_k<0><<<dim3(NTILE, NCH), 256, 0, stream>>>(A, relP, tM, cnt, out);
  // 3. preM += D_chunk @ tM; last block per tile: SELU + L2-norm -> out
  gemm_splitk_k<1><<<dim3(NTILE, NCH), 256, 0, stream>>>(D, tM, preM, cnt, out);
}